// Round 1
// baseline (3178.907 us; speedup 1.0000x reference)
//
#include <hip/hip_runtime.h>

#define NN 100000
#define NE 1600000
#define NB 2
#define CH 8
#define HID 16

__device__ __forceinline__ unsigned int ford(float f) {
    unsigned int u = __float_as_uint(f);
    return (u & 0x80000000u) ? ~u : (u | 0x80000000u);
}
__device__ __forceinline__ float dford(unsigned int u) {
    u = (u & 0x80000000u) ? (u & 0x7FFFFFFFu) : ~u;
    return __uint_as_float(u);
}
#define NEG_ORD 0x007FFFFFu  // ford(-inf)

__device__ __forceinline__ float soft_clamp(float x) {
    float y = x * 1e-6f;
    return x * (1.0f - 0.33333333f * y * y);  // 1e6*tanh(x/1e6) for small |x|
}

__device__ __forceinline__ void load8(const float* __restrict__ p, float* x) {
    float4 a = ((const float4*)p)[0];
    float4 b = ((const float4*)p)[1];
    x[0]=a.x; x[1]=a.y; x[2]=a.z; x[3]=a.w; x[4]=b.x; x[5]=b.y; x[6]=b.z; x[7]=b.w;
}
__device__ __forceinline__ void store8(float* __restrict__ p, const float* x) {
    ((float4*)p)[0] = make_float4(x[0],x[1],x[2],x[3]);
    ((float4*)p)[1] = make_float4(x[4],x[5],x[6],x[7]);
}

// ---------------- kernel A: att MLP per node + init accumulators ----------------
__global__ void att_init_kernel(const float* __restrict__ nodes,
                                const float* __restrict__ w1, const float* __restrict__ b1,
                                const float* __restrict__ w2, const float* __restrict__ b2,
                                float* __restrict__ att,
                                unsigned int* __restrict__ maxa, unsigned int* __restrict__ maxb,
                                float* __restrict__ dena, float* __restrict__ denb,
                                float* __restrict__ numa, float* __restrict__ numb) {
    __shared__ float sw1[CH*HID], sb1[HID], sw2[HID*32], sb2[32];
    int tid = threadIdx.x;
    for (int i = tid; i < CH*HID; i += 256) sw1[i] = w1[i];
    for (int i = tid; i < HID; i += 256) sb1[i] = b1[i];
    for (int i = tid; i < HID*32; i += 256) sw2[i] = w2[i];
    for (int i = tid; i < 32; i += 256) sb2[i] = b2[i];
    __syncthreads();
    int n = blockIdx.x * 256 + tid;
    if (n >= NN) return;
    int b = blockIdx.y;
    size_t base = (size_t)b * NN + n;

    float x[CH];
    load8(nodes + base * CH, x);
    float h[HID];
#pragma unroll
    for (int j = 0; j < HID; j++) {
        float acc = sb1[j];
#pragma unroll
        for (int i = 0; i < CH; i++) acc += x[i] * sw1[i*HID + j];
        h[j] = tanhf(acc);
    }
    float o[32];
#pragma unroll
    for (int k = 0; k < 32; k++) {
        float acc = sb2[k];
#pragma unroll
        for (int j = 0; j < HID; j++) acc += h[j] * sw2[j*32 + k];
        o[k] = acc;
    }
    store8(att + base*32,      o);
    store8(att + base*32 + 8,  o+8);
    store8(att + base*32 + 16, o+16);
    store8(att + base*32 + 24, o+24);

    maxa[base] = NEG_ORD; maxb[base] = NEG_ORD;
    dena[base] = 0.0f;    denb[base] = 0.0f;
#pragma unroll
    for (int c = 0; c < CH; c++) { numa[base*CH + c] = 0.0f; numb[base*CH + c] = 0.0f; }
}

// ---------------- kernel B: logits + segment max ----------------
__global__ void logit_max_kernel(const int* __restrict__ src, const int* __restrict__ tgt,
                                 const float* __restrict__ att,
                                 unsigned int* __restrict__ maxa, unsigned int* __restrict__ maxb) {
    int e = blockIdx.x * 256 + threadIdx.x;
    if (e >= NE) return;
    int b = blockIdx.y;
    int s = src[e], t = tgt[e];
    size_t sbase = (size_t)b * NN + s, tbase = (size_t)b * NN + t;
    float akq[16], bkq[16];
    load8(att + sbase*32,      akq);      // a_key
    load8(att + sbase*32 + 8,  akq + 8);  // a_query
    load8(att + tbase*32 + 16, bkq);      // b_key
    load8(att + tbase*32 + 24, bkq + 8);  // b_query
    const float scale = 0.35355339059327373f;
    float la = 0.0f, lb = 0.0f;
#pragma unroll
    for (int c = 0; c < CH; c++) { la += akq[8+c] * bkq[c]; lb += bkq[8+c] * akq[c]; }
    la *= scale; lb *= scale;
    atomicMax(&maxa[sbase], ford(la));
    atomicMax(&maxb[tbase], ford(lb));
}

// ---------------- kernel C: msg MLP, new_edges, exp + atomic accumulate ----------------
__global__ void edge_kernel(const float* __restrict__ nodes, const float* __restrict__ edges,
                            const int* __restrict__ src, const int* __restrict__ tgt,
                            const float* __restrict__ w1, const float* __restrict__ b1,
                            const float* __restrict__ w2, const float* __restrict__ b2,
                            const float* __restrict__ att,
                            const unsigned int* __restrict__ maxa, const unsigned int* __restrict__ maxb,
                            float* __restrict__ dena, float* __restrict__ denb,
                            float* __restrict__ numa, float* __restrict__ numb,
                            float* __restrict__ out_edges) {
    __shared__ float sw1[24*HID], sb1[HID], sw2[HID*24], sb2[24];
    int tid = threadIdx.x;
    for (int i = tid; i < 24*HID; i += 256) sw1[i] = w1[i];
    for (int i = tid; i < HID; i += 256) sb1[i] = b1[i];
    for (int i = tid; i < HID*24; i += 256) sw2[i] = w2[i];
    for (int i = tid; i < 24; i += 256) sb2[i] = b2[i];
    __syncthreads();
    int e = blockIdx.x * 256 + tid;
    if (e >= NE) return;
    int b = blockIdx.y;
    int s = src[e], t = tgt[e];
    size_t sbase = (size_t)b * NN + s, tbase = (size_t)b * NN + t;
    size_t ebase = (size_t)b * NE + e;

    float in[24];
    load8(nodes + sbase*CH, in);
    load8(nodes + tbase*CH, in + 8);
    load8(edges + ebase*CH, in + 16);

    float h[HID];
#pragma unroll
    for (int j = 0; j < HID; j++) {
        float acc = sb1[j];
#pragma unroll
        for (int i = 0; i < 24; i++) acc += in[i] * sw1[i*HID + j];
        h[j] = tanhf(acc);
    }
    float m[24];
#pragma unroll
    for (int k = 0; k < 24; k++) {
        float acc = sb2[k];
#pragma unroll
        for (int j = 0; j < HID; j++) acc += h[j] * sw2[j*24 + k];
        m[k] = acc;
    }

    float eo[CH];
#pragma unroll
    for (int c = 0; c < CH; c++) eo[c] = soft_clamp(in[16+c] + m[16+c]);
    store8(out_edges + ebase*CH, eo);

    float akq[16], bkq[16];
    load8(att + sbase*32,      akq);
    load8(att + sbase*32 + 8,  akq + 8);
    load8(att + tbase*32 + 16, bkq);
    load8(att + tbase*32 + 24, bkq + 8);
    const float scale = 0.35355339059327373f;
    float la = 0.0f, lb = 0.0f;
#pragma unroll
    for (int c = 0; c < CH; c++) { la += akq[8+c] * bkq[c]; lb += bkq[8+c] * akq[c]; }
    la *= scale; lb *= scale;

    float exa = __expf(la - dford(maxa[sbase]));
    float exb = __expf(lb - dford(maxb[tbase]));
    unsafeAtomicAdd(&dena[sbase], exa);
    unsafeAtomicAdd(&denb[tbase], exb);
#pragma unroll
    for (int c = 0; c < CH; c++) unsafeAtomicAdd(&numa[sbase*CH + c], exa * m[c]);
#pragma unroll
    for (int c = 0; c < CH; c++) unsafeAtomicAdd(&numb[tbase*CH + c], exb * m[8+c]);
}

// ---------------- kernel D: aggregate, upd MLP, new_nodes ----------------
__global__ void node_out_kernel(const float* __restrict__ nodes,
                                const float* __restrict__ dena, const float* __restrict__ denb,
                                const float* __restrict__ numa, const float* __restrict__ numb,
                                const float* __restrict__ w1, const float* __restrict__ b1,
                                const float* __restrict__ w2, const float* __restrict__ b2,
                                float* __restrict__ out_nodes) {
    __shared__ float sw1[24*HID], sb1[HID], sw2[HID*CH], sb2[CH];
    int tid = threadIdx.x;
    for (int i = tid; i < 24*HID; i += 256) sw1[i] = w1[i];
    for (int i = tid; i < HID; i += 256) sb1[i] = b1[i];
    for (int i = tid; i < HID*CH; i += 256) sw2[i] = w2[i];
    for (int i = tid; i < CH; i += 256) sb2[i] = b2[i];
    __syncthreads();
    int n = blockIdx.x * 256 + tid;
    if (n >= NN) return;
    int b = blockIdx.y;
    size_t base = (size_t)b * NN + n;

    float in[24];
    load8(nodes + base*CH, in);
    float da = dena[base] + 1e-10f, db = denb[base] + 1e-10f;
#pragma unroll
    for (int c = 0; c < CH; c++) {
        in[8 + c]  = numa[base*CH + c] / da;
        in[16 + c] = numb[base*CH + c] / db;
    }
    float h[HID];
#pragma unroll
    for (int j = 0; j < HID; j++) {
        float acc = sb1[j];
#pragma unroll
        for (int i = 0; i < 24; i++) acc += in[i] * sw1[i*HID + j];
        h[j] = tanhf(acc);
    }
    float o[CH];
#pragma unroll
    for (int k = 0; k < CH; k++) {
        float acc = sb2[k];
#pragma unroll
        for (int j = 0; j < HID; j++) acc += h[j] * sw2[j*CH + k];
        o[k] = acc;
    }
    float no[CH];
#pragma unroll
    for (int c = 0; c < CH; c++) no[c] = soft_clamp(in[c] + o[c]);
    store8(out_nodes + base*CH, no);
}

extern "C" void kernel_launch(void* const* d_in, const int* in_sizes, int n_in,
                              void* d_out, int out_size, void* d_ws, size_t ws_size,
                              hipStream_t stream) {
    const float* nodes  = (const float*)d_in[0];
    const float* edges  = (const float*)d_in[1];
    const float* msg_w1 = (const float*)d_in[2];
    const float* msg_b1 = (const float*)d_in[3];
    const float* msg_w2 = (const float*)d_in[4];
    const float* msg_b2 = (const float*)d_in[5];
    const float* att_w1 = (const float*)d_in[6];
    const float* att_b1 = (const float*)d_in[7];
    const float* att_w2 = (const float*)d_in[8];
    const float* att_b2 = (const float*)d_in[9];
    const float* upd_w1 = (const float*)d_in[10];
    const float* upd_b1 = (const float*)d_in[11];
    const float* upd_w2 = (const float*)d_in[12];
    const float* upd_b2 = (const float*)d_in[13];
    const int*   sources = (const int*)d_in[14];
    const int*   targets = (const int*)d_in[15];

    float* out       = (float*)d_out;
    float* out_nodes = out;
    float* out_edges = out + (size_t)NB * NN * CH;

    size_t nb = (size_t)NB * NN;
    float* ws = (float*)d_ws;
    float*        att  = ws;                          // nb*32
    unsigned int* maxa = (unsigned int*)(att + nb*32);// nb
    unsigned int* maxb = maxa + nb;                   // nb
    float*        dena = (float*)(maxb + nb);         // nb
    float*        denb = dena + nb;                   // nb
    float*        numa = denb + nb;                   // nb*8
    float*        numb = numa + nb*CH;                // nb*8

    dim3 gn((NN + 255) / 256, NB);
    dim3 ge((NE + 255) / 256, NB);

    att_init_kernel<<<gn, 256, 0, stream>>>(nodes, att_w1, att_b1, att_w2, att_b2,
                                            att, maxa, maxb, dena, denb, numa, numb);
    logit_max_kernel<<<ge, 256, 0, stream>>>(sources, targets, att, maxa, maxb);
    edge_kernel<<<ge, 256, 0, stream>>>(nodes, edges, sources, targets,
                                        msg_w1, msg_b1, msg_w2, msg_b2,
                                        att, maxa, maxb, dena, denb, numa, numb, out_edges);
    node_out_kernel<<<gn, 256, 0, stream>>>(nodes, dena, denb, numa, numb,
                                            upd_w1, upd_b1, upd_w2, upd_b2, out_nodes);
}

// Round 2
// 1028.136 us; speedup vs baseline: 3.0919x; 3.0919x over previous
//
#include <hip/hip_runtime.h>

#define NN 100000
#define NE 1600000
#define NB 2
#define CH 8
#define HID 16
#define NTILES 98   // ceil(NN/1024)

__device__ __forceinline__ float soft_clamp(float x) {
    float y = x * 1e-6f;
    return x * (1.0f - 0.33333333f * y * y);  // 1e6*tanh(x/1e6), |x| small
}
__device__ __forceinline__ void load8(const float* __restrict__ p, float* x) {
    float4 a = ((const float4*)p)[0];
    float4 b = ((const float4*)p)[1];
    x[0]=a.x; x[1]=a.y; x[2]=a.z; x[3]=a.w; x[4]=b.x; x[5]=b.y; x[6]=b.z; x[7]=b.w;
}
__device__ __forceinline__ void store8(float* __restrict__ p, const float* x) {
    ((float4*)p)[0] = make_float4(x[0],x[1],x[2],x[3]);
    ((float4*)p)[1] = make_float4(x[4],x[5],x[6],x[7]);
}
__device__ __forceinline__ unsigned int bfu(float x) {  // f32 -> bf16 bits (RNE)
    unsigned int u = __float_as_uint(x);
    return (u + 0x7fffu + ((u >> 16) & 1u)) >> 16;
}
__device__ __forceinline__ float ubf(unsigned int u) { return __uint_as_float(u << 16); }

// ---------------- att MLP per node ----------------
__global__ void att_kernel(const float* __restrict__ nodes,
                           const float* __restrict__ w1, const float* __restrict__ b1,
                           const float* __restrict__ w2, const float* __restrict__ b2,
                           float* __restrict__ att) {
    __shared__ float sw1[CH*HID], sb1[HID], sw2[HID*32], sb2[32];
    int tid = threadIdx.x;
    for (int i = tid; i < CH*HID; i += 256) sw1[i] = w1[i];
    for (int i = tid; i < HID; i += 256) sb1[i] = b1[i];
    for (int i = tid; i < HID*32; i += 256) sw2[i] = w2[i];
    for (int i = tid; i < 32; i += 256) sb2[i] = b2[i];
    __syncthreads();
    int n = blockIdx.x * 256 + tid;
    if (n >= NN) return;
    int b = blockIdx.y;
    size_t base = (size_t)b * NN + n;

    float x[CH];
    load8(nodes + base * CH, x);
    float h[HID];
#pragma unroll
    for (int j = 0; j < HID; j++) {
        float acc = sb1[j];
#pragma unroll
        for (int i = 0; i < CH; i++) acc += x[i] * sw1[i*HID + j];
        h[j] = tanhf(acc);
    }
    float o[32];
#pragma unroll
    for (int k = 0; k < 32; k++) {
        float acc = sb2[k];
#pragma unroll
        for (int j = 0; j < HID; j++) acc += h[j] * sw2[j*32 + k];
        o[k] = acc;
    }
    store8(att + base*32,      o);
    store8(att + base*32 + 8,  o+8);
    store8(att + base*32 + 16, o+16);
    store8(att + base*32 + 24, o+24);
}

// ---------------- CSR build: histogram ----------------
__global__ void hist_kernel(const int* __restrict__ src, const int* __restrict__ tgt,
                            int* __restrict__ cntA, int* __restrict__ cntB) {
    int e = blockIdx.x * 256 + threadIdx.x;
    if (e >= NE) return;
    atomicAdd(&cntA[src[e]], 1);
    atomicAdd(&cntB[tgt[e]], 1);
}

// ---------------- CSR build: hierarchical exclusive scan ----------------
__global__ void scan_part_kernel(const int* __restrict__ cnt, int* __restrict__ part) {
    int y = blockIdx.y;
    const int* c = cnt + (size_t)y * NN;
    __shared__ int s[256];
    int t = threadIdx.x, bx = blockIdx.x;
    int base = bx * 1024 + t * 4;
    int sum = 0;
#pragma unroll
    for (int k = 0; k < 4; k++) { int i = base + k; sum += (i < NN) ? c[i] : 0; }
    s[t] = sum; __syncthreads();
    for (int off = 128; off > 0; off >>= 1) { if (t < off) s[t] += s[t + off]; __syncthreads(); }
    if (t == 0) part[y * 256 + bx] = s[0];
}

__global__ void scan_top_kernel(int* __restrict__ part,
                                int* __restrict__ rowA, int* __restrict__ rowB) {
    int y = blockIdx.y; int t = threadIdx.x;
    __shared__ int s[256];
    int v = (t < NTILES) ? part[y * 256 + t] : 0;
    s[t] = v; __syncthreads();
    for (int off = 1; off < 256; off <<= 1) {
        int x = (t >= off) ? s[t - off] : 0;
        __syncthreads();
        s[t] += x;
        __syncthreads();
    }
    part[y * 256 + t] = t ? s[t - 1] : 0;
    if (t == 0) (y ? rowB : rowA)[NN] = NE;
}

__global__ void scan_down_kernel(const int* __restrict__ cnt, const int* __restrict__ part,
                                 int* __restrict__ rowA, int* __restrict__ rowB,
                                 int* __restrict__ curA, int* __restrict__ curB) {
    int y = blockIdx.y;
    const int* c = cnt + (size_t)y * NN;
    int* row = y ? rowB : rowA;
    int* cur = y ? curB : curA;
    __shared__ int s[256];
    int t = threadIdx.x, bx = blockIdx.x;
    int base = bx * 1024 + t * 4;
    int v[4]; int tsum = 0;
#pragma unroll
    for (int k = 0; k < 4; k++) { int i = base + k; v[k] = (i < NN) ? c[i] : 0; tsum += v[k]; }
    s[t] = tsum; __syncthreads();
    for (int off = 1; off < 256; off <<= 1) {
        int x = (t >= off) ? s[t - off] : 0;
        __syncthreads();
        s[t] += x;
        __syncthreads();
    }
    int run = part[y * 256 + bx] + s[t] - tsum;
#pragma unroll
    for (int k = 0; k < 4; k++) {
        int i = base + k;
        if (i < NN) { row[i] = run; cur[i] = run; }
        run += v[k];
    }
}

// ---------------- CSR build: scatter edge ids ----------------
__global__ void scatter_kernel(const int* __restrict__ src, const int* __restrict__ tgt,
                               int* __restrict__ curA, int* __restrict__ curB,
                               int* __restrict__ eidA, int* __restrict__ eidB) {
    int e = blockIdx.x * 256 + threadIdx.x;
    if (e >= NE) return;
    int p1 = atomicAdd(&curA[src[e]], 1); eidA[p1] = e;
    int p2 = atomicAdd(&curB[tgt[e]], 1); eidB[p2] = e;
}

// ---------------- edge: msg MLP, new_edges, payload stores (no atomics) ----------------
__global__ void edge_kernel(const float* __restrict__ nodes, const float* __restrict__ edges,
                            const int* __restrict__ src, const int* __restrict__ tgt,
                            const float* __restrict__ w1, const float* __restrict__ b1,
                            const float* __restrict__ w2, const float* __restrict__ b2,
                            const float* __restrict__ att,
                            float* __restrict__ out_edges,
                            float* __restrict__ logitA, float* __restrict__ logitB,
                            ushort* __restrict__ mA, ushort* __restrict__ mB) {
    __shared__ float sw1[24*HID], sb1[HID], sw2[HID*24], sb2[24];
    int tid = threadIdx.x;
    for (int i = tid; i < 24*HID; i += 256) sw1[i] = w1[i];
    for (int i = tid; i < HID; i += 256) sb1[i] = b1[i];
    for (int i = tid; i < HID*24; i += 256) sw2[i] = w2[i];
    for (int i = tid; i < 24; i += 256) sb2[i] = b2[i];
    __syncthreads();
    int e = blockIdx.x * 256 + tid;
    if (e >= NE) return;
    int b = blockIdx.y;
    int s = src[e], t = tgt[e];
    size_t sbase = (size_t)b * NN + s, tbase = (size_t)b * NN + t;
    size_t ebase = (size_t)b * NE + e;

    float in[24];
    load8(nodes + sbase*CH, in);
    load8(nodes + tbase*CH, in + 8);
    load8(edges + ebase*CH, in + 16);

    float h[HID];
#pragma unroll
    for (int j = 0; j < HID; j++) {
        float acc = sb1[j];
#pragma unroll
        for (int i = 0; i < 24; i++) acc += in[i] * sw1[i*HID + j];
        h[j] = tanhf(acc);
    }
    float m[24];
#pragma unroll
    for (int k = 0; k < 24; k++) {
        float acc = sb2[k];
#pragma unroll
        for (int j = 0; j < HID; j++) acc += h[j] * sw2[j*24 + k];
        m[k] = acc;
    }

    float eo[CH];
#pragma unroll
    for (int c = 0; c < CH; c++) eo[c] = soft_clamp(in[16+c] + m[16+c]);
    store8(out_edges + ebase*CH, eo);

    float akq[16], bkq[16];
    load8(att + sbase*32,      akq);      // a_key(src)
    load8(att + sbase*32 + 8,  akq + 8);  // a_query(src)
    load8(att + tbase*32 + 16, bkq);      // b_key(tgt)
    load8(att + tbase*32 + 24, bkq + 8);  // b_query(tgt)
    const float scale = 0.35355339059327373f;
    float la = 0.0f, lb = 0.0f;
#pragma unroll
    for (int c = 0; c < CH; c++) { la += akq[8+c] * bkq[c]; lb += bkq[8+c] * akq[c]; }
    la *= scale; lb *= scale;

    logitA[ebase] = la;
    logitB[ebase] = lb;
    uint4 pa, pb;
    pa.x = bfu(m[0]) | (bfu(m[1]) << 16);
    pa.y = bfu(m[2]) | (bfu(m[3]) << 16);
    pa.z = bfu(m[4]) | (bfu(m[5]) << 16);
    pa.w = bfu(m[6]) | (bfu(m[7]) << 16);
    pb.x = bfu(m[8])  | (bfu(m[9])  << 16);
    pb.y = bfu(m[10]) | (bfu(m[11]) << 16);
    pb.z = bfu(m[12]) | (bfu(m[13]) << 16);
    pb.w = bfu(m[14]) | (bfu(m[15]) << 16);
    *(uint4*)(mA + ebase*8) = pa;
    *(uint4*)(mB + ebase*8) = pb;
}

// ---------------- node: CSR online-softmax aggregation + upd MLP ----------------
__global__ void node_kernel(const float* __restrict__ nodes,
                            const int* __restrict__ rowA, const int* __restrict__ rowB,
                            const int* __restrict__ eidA, const int* __restrict__ eidB,
                            const float* __restrict__ logitA, const float* __restrict__ logitB,
                            const ushort* __restrict__ mA, const ushort* __restrict__ mB,
                            const float* __restrict__ w1, const float* __restrict__ b1,
                            const float* __restrict__ w2, const float* __restrict__ b2,
                            float* __restrict__ out_nodes) {
    __shared__ float sw1[24*HID], sb1[HID], sw2[HID*CH], sb2[CH];
    int tid = threadIdx.x;
    for (int i = tid; i < 24*HID; i += 256) sw1[i] = w1[i];
    for (int i = tid; i < HID; i += 256) sb1[i] = b1[i];
    for (int i = tid; i < HID*CH; i += 256) sw2[i] = w2[i];
    for (int i = tid; i < CH; i += 256) sb2[i] = b2[i];
    __syncthreads();
    int n = blockIdx.x * 256 + tid;
    if (n >= NN) return;
    int b = blockIdx.y;
    size_t base = (size_t)b * NN + n;

    float in[24];
    load8(nodes + base*CH, in);

    // aggregate A (segments = sources)
    {
        int beg = rowA[n], end = rowA[n+1];
        float mx = -1e30f, den = 0.0f, num[CH];
#pragma unroll
        for (int c = 0; c < CH; c++) num[c] = 0.0f;
        for (int i = beg; i < end; ++i) {
            int e = eidA[i];
            size_t eb = (size_t)b * NE + e;
            float l = logitA[eb];
            uint4 v = *(const uint4*)(mA + eb*8);
            float w;
            if (l > mx) {
                float r = __expf(mx - l);
                den *= r;
#pragma unroll
                for (int c = 0; c < CH; c++) num[c] *= r;
                mx = l; w = 1.0f;
            } else {
                w = __expf(l - mx);
            }
            den += w;
            float mm[8];
            mm[0]=ubf(v.x & 0xffffu); mm[1]=ubf(v.x >> 16);
            mm[2]=ubf(v.y & 0xffffu); mm[3]=ubf(v.y >> 16);
            mm[4]=ubf(v.z & 0xffffu); mm[5]=ubf(v.z >> 16);
            mm[6]=ubf(v.w & 0xffffu); mm[7]=ubf(v.w >> 16);
#pragma unroll
            for (int c = 0; c < CH; c++) num[c] += w * mm[c];
        }
        float inv = 1.0f / (den + 1e-10f);
#pragma unroll
        for (int c = 0; c < CH; c++) in[8+c] = num[c] * inv;
    }
    // aggregate B (segments = targets)
    {
        int beg = rowB[n], end = rowB[n+1];
        float mx = -1e30f, den = 0.0f, num[CH];
#pragma unroll
        for (int c = 0; c < CH; c++) num[c] = 0.0f;
        for (int i = beg; i < end; ++i) {
            int e = eidB[i];
            size_t eb = (size_t)b * NE + e;
            float l = logitB[eb];
            uint4 v = *(const uint4*)(mB + eb*8);
            float w;
            if (l > mx) {
                float r = __expf(mx - l);
                den *= r;
#pragma unroll
                for (int c = 0; c < CH; c++) num[c] *= r;
                mx = l; w = 1.0f;
            } else {
                w = __expf(l - mx);
            }
            den += w;
            float mm[8];
            mm[0]=ubf(v.x & 0xffffu); mm[1]=ubf(v.x >> 16);
            mm[2]=ubf(v.y & 0xffffu); mm[3]=ubf(v.y >> 16);
            mm[4]=ubf(v.z & 0xffffu); mm[5]=ubf(v.z >> 16);
            mm[6]=ubf(v.w & 0xffffu); mm[7]=ubf(v.w >> 16);
#pragma unroll
            for (int c = 0; c < CH; c++) num[c] += w * mm[c];
        }
        float inv = 1.0f / (den + 1e-10f);
#pragma unroll
        for (int c = 0; c < CH; c++) in[16+c] = num[c] * inv;
    }

    float h[HID];
#pragma unroll
    for (int j = 0; j < HID; j++) {
        float acc = sb1[j];
#pragma unroll
        for (int i = 0; i < 24; i++) acc += in[i] * sw1[i*HID + j];
        h[j] = tanhf(acc);
    }
    float o[CH];
#pragma unroll
    for (int k = 0; k < CH; k++) {
        float acc = sb2[k];
#pragma unroll
        for (int j = 0; j < HID; j++) acc += h[j] * sw2[j*CH + k];
        o[k] = acc;
    }
    float no[CH];
#pragma unroll
    for (int c = 0; c < CH; c++) no[c] = soft_clamp(in[c] + o[c]);
    store8(out_nodes + base*CH, no);
}

extern "C" void kernel_launch(void* const* d_in, const int* in_sizes, int n_in,
                              void* d_out, int out_size, void* d_ws, size_t ws_size,
                              hipStream_t stream) {
    const float* nodes  = (const float*)d_in[0];
    const float* edges  = (const float*)d_in[1];
    const float* msg_w1 = (const float*)d_in[2];
    const float* msg_b1 = (const float*)d_in[3];
    const float* msg_w2 = (const float*)d_in[4];
    const float* msg_b2 = (const float*)d_in[5];
    const float* att_w1 = (const float*)d_in[6];
    const float* att_b1 = (const float*)d_in[7];
    const float* att_w2 = (const float*)d_in[8];
    const float* att_b2 = (const float*)d_in[9];
    const float* upd_w1 = (const float*)d_in[10];
    const float* upd_b1 = (const float*)d_in[11];
    const float* upd_w2 = (const float*)d_in[12];
    const float* upd_b2 = (const float*)d_in[13];
    const int*   sources = (const int*)d_in[14];
    const int*   targets = (const int*)d_in[15];

    float* out       = (float*)d_out;
    float* out_nodes = out;
    float* out_edges = out + (size_t)NB * NN * CH;

    char* wp = (char*)d_ws;
    size_t off = 0;
    auto take = [&](size_t bytes) -> char* {
        char* p = wp + off;
        off = (off + bytes + 255) & ~(size_t)255;
        return p;
    };
    float*  att    = (float*)take((size_t)NB * NN * 32 * 4);
    int*    cnt    = (int*)take((size_t)2 * NN * 4);       // cntA | cntB
    int*    rowA   = (int*)take((size_t)(NN + 1) * 4);
    int*    rowB   = (int*)take((size_t)(NN + 1) * 4);
    int*    curA   = (int*)take((size_t)NN * 4);
    int*    curB   = (int*)take((size_t)NN * 4);
    int*    part   = (int*)take((size_t)2 * 256 * 4);
    int*    eidA   = (int*)take((size_t)NE * 4);
    int*    eidB   = (int*)take((size_t)NE * 4);
    float*  logitA = (float*)take((size_t)NB * NE * 4);
    float*  logitB = (float*)take((size_t)NB * NE * 4);
    ushort* mA     = (ushort*)take((size_t)NB * NE * 8 * 2);
    ushort* mB     = (ushort*)take((size_t)NB * NE * 8 * 2);
    int* cntA = cnt, *cntB = cnt + NN;

    dim3 gn((NN + 255) / 256, NB);
    dim3 ge((NE + 255) / 256, NB);
    dim3 ge1((NE + 255) / 256);
    dim3 gs(NTILES, 2);
    dim3 gt(1, 2);

    hipMemsetAsync(cnt, 0, (size_t)2 * NN * 4, stream);
    att_kernel<<<gn, 256, 0, stream>>>(nodes, att_w1, att_b1, att_w2, att_b2, att);
    hist_kernel<<<ge1, 256, 0, stream>>>(sources, targets, cntA, cntB);
    scan_part_kernel<<<gs, 256, 0, stream>>>(cnt, part);
    scan_top_kernel<<<gt, 256, 0, stream>>>(part, rowA, rowB);
    scan_down_kernel<<<gs, 256, 0, stream>>>(cnt, part, rowA, rowB, curA, curB);
    scatter_kernel<<<ge1, 256, 0, stream>>>(sources, targets, curA, curB, eidA, eidB);
    edge_kernel<<<ge, 256, 0, stream>>>(nodes, edges, sources, targets,
                                        msg_w1, msg_b1, msg_w2, msg_b2, att,
                                        out_edges, logitA, logitB, mA, mB);
    node_kernel<<<gn, 256, 0, stream>>>(nodes, rowA, rowB, eidA, eidB,
                                        logitA, logitB, mA, mB,
                                        upd_w1, upd_b1, upd_w2, upd_b2, out_nodes);
}